// Round 16
// baseline (83.178 us; speedup 1.0000x reference)
//
#include <hip/hip_runtime.h>
#include <hip/hip_bf16.h>
#include <cstdint>

#define SEQ   2048
#define HD    64
#define NBH   32
#define QBLK  64
#define KVBLK 64
#define NQT   (SEQ / QBLK)  // 32
#define LDK   80            // 160B rows: bank-group = (2*row + chunk) mod 8 ->
                            // uniform for K-frag reads, V-frag reads, writes
// scale = 1/sqrt(64) * log2(e)  (softmax in exp2 domain)
#define QSC   0.18033688011112042f

typedef __attribute__((ext_vector_type(8))) short short8;
typedef __attribute__((ext_vector_type(4))) float floatx4;

#if __has_builtin(__builtin_amdgcn_exp2f)
#define EXP2(x) __builtin_amdgcn_exp2f(x)
#else
#define EXP2(x) __expf((x) * 0.69314718055994531f)
#endif

static __device__ __forceinline__ short f2bf(float f) {
    union { float f; unsigned u; } x; x.f = f;
    return (short)((x.u + 0x7fffu + ((x.u >> 16) & 1u)) >> 16);  // RNE
}
static __device__ __forceinline__ unsigned pkbf(float a, float b) {
    __hip_bfloat162 h = __float22bfloat162_rn(make_float2(a, b));
    union { __hip_bfloat162 h; unsigned u; } c; c.h = h; return c.u;
}

// ---------------- fused prep kernel (proven) ----------------

__global__ __launch_bounds__(256)
void prep_kv(const float* __restrict__ K, const float* __restrict__ V,
             short* __restrict__ Kb, short* __restrict__ Vt) {
    __shared__ __align__(16) short Vs[64][72];
    const int tid = threadIdx.x;
    const int bh = blockIdx.x >> 5;
    const int t  = blockIdx.x & 31;
    const size_t tbase = ((size_t)bh * SEQ + (size_t)t * 64) * HD;

    {
        const float* src = K + tbase;
        short* dst = Kb + tbase;
        #pragma unroll
        for (int i = 0; i < 2; ++i) {
            int off = (i * 256 + tid) * 8;
            float4 a = *(const float4*)(src + off);
            float4 b = *(const float4*)(src + off + 4);
            union { unsigned u[4]; short8 s; } cv;
            cv.u[0] = pkbf(a.x, a.y); cv.u[1] = pkbf(a.z, a.w);
            cv.u[2] = pkbf(b.x, b.y); cv.u[3] = pkbf(b.z, b.w);
            *(short8*)(dst + off) = cv.s;
        }
    }
    {
        const float* src = V + tbase;
        #pragma unroll
        for (int i = 0; i < 4; ++i) {
            int idx = i * 256 + tid;
            int r = idx >> 4; int c = (idx & 15) * 4;
            float4 f = *(const float4*)(src + r * HD + c);
            Vs[c + 0][r] = f2bf(f.x); Vs[c + 1][r] = f2bf(f.y);
            Vs[c + 2][r] = f2bf(f.z); Vs[c + 3][r] = f2bf(f.w);
        }
        __syncthreads();
        short* dst = Vt + (size_t)bh * HD * SEQ + t * 64;
        #pragma unroll
        for (int i = 0; i < 2; ++i) {
            int idx = i * 256 + tid;
            int d = idx >> 3; int j = idx & 7;
            short8 v = *(const short8*)&Vs[d][j * 8];
            *(short8*)(dst + (size_t)d * SEQ + j * 8) = v;
        }
    }
}

// ---------------- main attention kernel (v16) ----------------
// = v15 loop body (static-shift-free softmax P=exp2(S), zero-LDS P via K-row
// permutation {0,4,32,36}, l via ones-MFMA, LDK=80 conflict-free layout,
// reg-prefetch, 1024 heavy-first blocks) with SINGLE-BUFFERED K/V LDS:
// 20.5 KB/block (was 41) -> up to 8 blocks/CU resident (launch_bounds(256,8),
// VGPR<=64 cap, we use 52). Two barriers/tile: publish -> barrier(ready) ->
// prefetch+compute -> barrier(done). The extra barrier is hidden by the
// doubled block-level overlap.

__global__ __launch_bounds__(256, 8)
void fa_fwd_v16(const float* __restrict__ Q, const short* __restrict__ Kg,
                const short* __restrict__ Vtg, float* __restrict__ O)
{
    const int tid  = threadIdx.x;
    const int lane = tid & 63;
    const int wv   = tid >> 6;
    const int l15  = lane & 15;
    const int lg   = lane >> 4;
    const int lg4  = lg * 4;
    const int dofs = lg * 8;

    const int bh = blockIdx.x & (NBH - 1);
    const int qi = (NQT - 1) - (blockIdx.x >> 5);   // heavy tiles first
    const int qbase = qi * QBLK;

    const float* Qp = Q   + (size_t)bh * SEQ * HD;
    const short* Kp = Kg  + (size_t)bh * SEQ * HD;
    const short* Vp = Vtg + (size_t)bh * HD * SEQ;
    float*       Op = O   + (size_t)bh * SEQ * HD;

    __shared__ __align__(16) short K_lds[KVBLK][LDK];   // 10.24 KB
    __shared__ __align__(16) short Vt_lds[HD][LDK];     // 10.24 KB

    const int r0 = tid >> 3, j0 = tid & 7;
    const int r1 = r0 + 32;
    const int kg0 = r0 * HD + j0 * 8, kg1 = r1 * HD + j0 * 8;
    const int vg0 = r0 * SEQ + j0 * 8, vg1 = r1 * SEQ + j0 * 8;

    // permuted K-row base: call n reads row rowb + {0,4,32,36}[n]
    const int rowb = ((l15 & ~3) << 1) + (l15 & 3);   // 8*(l15>>2) + (l15&3)
    const int kb   = 8 * lg;                           // lane's k base

    // ---- Q fragments (B-operand), scale folded ----
    short8 qf0, qf1;
    {
        const float* src = Qp + (size_t)(qbase + wv * 16 + l15) * HD + dofs;
        union { unsigned u[4]; short8 s; } cv;
        float4 f0 = *(const float4*)(src);
        float4 f1 = *(const float4*)(src + 4);
        cv.u[0] = pkbf(f0.x * QSC, f0.y * QSC); cv.u[1] = pkbf(f0.z * QSC, f0.w * QSC);
        cv.u[2] = pkbf(f1.x * QSC, f1.y * QSC); cv.u[3] = pkbf(f1.z * QSC, f1.w * QSC);
        qf0 = cv.s;
        f0 = *(const float4*)(src + 32);
        f1 = *(const float4*)(src + 36);
        cv.u[0] = pkbf(f0.x * QSC, f0.y * QSC); cv.u[1] = pkbf(f0.z * QSC, f0.w * QSC);
        cv.u[2] = pkbf(f1.x * QSC, f1.y * QSC); cv.u[3] = pkbf(f1.z * QSC, f1.w * QSC);
        qf1 = cv.s;
    }

    // all-ones bf16 B-fragment for the l-accumulating MFMA
    short8 ones;
    #pragma unroll
    for (int j = 0; j < 8; ++j) ones[j] = (short)0x3F80;

    // ---- prologue: prefetch tile 0 into registers ----
    short8 krA = *(const short8*)(Kp + kg0);
    short8 krB = *(const short8*)(Kp + kg1);
    short8 vrA = *(const short8*)(Vp + vg0);
    short8 vrB = *(const short8*)(Vp + vg1);

    floatx4 o_acc[4], l_acc;
    #pragma unroll
    for (int dt = 0; dt < 4; ++dt)
        #pragma unroll
        for (int e = 0; e < 4; ++e) o_acc[dt][e] = 0.0f;
    #pragma unroll
    for (int e = 0; e < 4; ++e) l_acc[e] = 0.0f;

    for (int t = 0; t <= qi; ++t) {
        // ---- publish tile t (regs -> LDS), single buffer ----
        *(short8*)&K_lds[r0][j0 * 8]  = krA;
        *(short8*)&K_lds[r1][j0 * 8]  = krB;
        *(short8*)&Vt_lds[r0][j0 * 8] = vrA;
        *(short8*)&Vt_lds[r1][j0 * 8] = vrB;
        __syncthreads();   // tile t visible to all waves

        // ---- prefetch tile t+1 into regs; consumed at next publish ----
        if (t < qi) {
            const short* ks = Kp + (size_t)(t + 1) * KVBLK * HD;
            const short* vs = Vp + (t + 1) * KVBLK;
            krA = *(const short8*)(ks + kg0);
            krB = *(const short8*)(ks + kg1);
            vrA = *(const short8*)(vs + vg0);
            vrB = *(const short8*)(vs + vg1);
        }

        // ---- S^T = K (Q*scale)^T with permuted rows:
        //      s_acc[n][r] = S[k = kb + roff[n] + r][q = l15] ----
        const int roff[4] = {0, 4, 32, 36};
        floatx4 s_acc[4];
        __builtin_amdgcn_s_setprio(1);
        #pragma unroll
        for (int n = 0; n < 4; ++n) {
            const short* krow = &K_lds[rowb + roff[n]][0];
            const short8 k0 = *(const short8*)(krow + dofs);
            const short8 k1 = *(const short8*)(krow + dofs + 32);
            floatx4 acc = {0.0f, 0.0f, 0.0f, 0.0f};
            acc = __builtin_amdgcn_mfma_f32_16x16x32_bf16(k0, qf0, acc, 0, 0, 0);
            acc = __builtin_amdgcn_mfma_f32_16x16x32_bf16(k1, qf1, acc, 0, 0, 0);
            s_acc[n] = acc;
        }
        __builtin_amdgcn_s_setprio(0);

        // ---- causal mask (diagonal tile only): k_local > q_local ----
        if (t == qi) {
            const int qlocal = wv * 16 + l15;
            #pragma unroll
            for (int n = 0; n < 4; ++n)
                #pragma unroll
                for (int r = 0; r < 4; ++r)
                    if (kb + roff[n] + r > qlocal) s_acc[n][r] = -1e30f;
        }

        // ---- P = exp2(S): shift-free (constant cancels in 1/l) ----
        float p00 = EXP2(s_acc[0][0]), p01 = EXP2(s_acc[0][1]);
        float p02 = EXP2(s_acc[0][2]), p03 = EXP2(s_acc[0][3]);
        float p10 = EXP2(s_acc[1][0]), p11 = EXP2(s_acc[1][1]);
        float p12 = EXP2(s_acc[1][2]), p13 = EXP2(s_acc[1][3]);
        float p20 = EXP2(s_acc[2][0]), p21 = EXP2(s_acc[2][1]);
        float p22 = EXP2(s_acc[2][2]), p23 = EXP2(s_acc[2][3]);
        float p30 = EXP2(s_acc[3][0]), p31 = EXP2(s_acc[3][1]);
        float p32 = EXP2(s_acc[3][2]), p33 = EXP2(s_acc[3][3]);

        // ---- pack P into PV A-fragments (in-register, zero LDS) ----
        short8 p0, p1;
        {
            union { unsigned u[4]; short8 s; } c0, c1;
            c0.u[0] = pkbf(p00, p01); c0.u[1] = pkbf(p02, p03);   // k = kb+0..3
            c0.u[2] = pkbf(p10, p11); c0.u[3] = pkbf(p12, p13);   // k = kb+4..7
            c1.u[0] = pkbf(p20, p21); c1.u[1] = pkbf(p22, p23);   // k = 32+kb+0..3
            c1.u[2] = pkbf(p30, p31); c1.u[3] = pkbf(p32, p33);   // k = 32+kb+4..7
            p0 = c0.s; p1 = c1.s;
        }

        // ---- O += P V ; l += P * ones (matrix pipe does the row-sum) ----
        __builtin_amdgcn_s_setprio(1);
        #pragma unroll
        for (int dt = 0; dt < 4; ++dt) {
            const short8 v0 = *(const short8*)&Vt_lds[dt * 16 + l15][dofs];
            const short8 v1 = *(const short8*)&Vt_lds[dt * 16 + l15][dofs + 32];
            o_acc[dt] = __builtin_amdgcn_mfma_f32_16x16x32_bf16(p0, v0, o_acc[dt], 0, 0, 0);
            o_acc[dt] = __builtin_amdgcn_mfma_f32_16x16x32_bf16(p1, v1, o_acc[dt], 0, 0, 0);
        }
        l_acc = __builtin_amdgcn_mfma_f32_16x16x32_bf16(p0, ones, l_acc, 0, 0, 0);
        l_acc = __builtin_amdgcn_mfma_f32_16x16x32_bf16(p1, ones, l_acc, 0, 0, 0);
        __builtin_amdgcn_s_setprio(0);

        __syncthreads();   // all waves done reading tile t before re-publish
    }

    // ---- finalize: l_acc[e] = l[q = lg4+e] in every lane; no shuffles ----
    #pragma unroll
    for (int e = 0; e < 4; ++e) {
        const float li = 1.0f / l_acc[e];
        const int row = qbase + wv * 16 + lg4 + e;
        #pragma unroll
        for (int dt = 0; dt < 4; ++dt)
            Op[(size_t)row * HD + dt * 16 + l15] = o_acc[dt][e] * li;
    }
}

// ---------------- fallback (round-1 kernel, proven) if ws too small ----------------

__global__ __launch_bounds__(256, 2)
void fa_fwd_v1(const float* __restrict__ Q, const float* __restrict__ K,
               const float* __restrict__ V, float* __restrict__ O)
{
    const int tid  = threadIdx.x;
    const int lane = tid & 63;
    const int wv   = tid >> 6;
    const int l15  = lane & 15;
    const int lg   = lane >> 4;
    const int dofs = lg * 8;
    const int bh = blockIdx.x & (NBH - 1);
    const int qi = 31 - (blockIdx.x >> 5);
    const size_t base = (size_t)bh * SEQ * HD;
    const float* Qp = Q + base; const float* Kp = K + base;
    const float* Vp = V + base; float* Op = O + base;
    const int qbase = qi * 64;
    __shared__ __align__(16) short K_lds[64][72];
    __shared__ __align__(16) short Vt_lds[HD][72];
    __shared__ __align__(16) short P_lds[4][16][72];
    short8 qfrag[2];
    {
        const float* src = Qp + (size_t)(qbase + wv * 16 + l15) * HD + dofs;
        #pragma unroll
        for (int c = 0; c < 2; ++c) {
            float4 f0 = *(const float4*)(src + 32 * c);
            float4 f1 = *(const float4*)(src + 32 * c + 4);
            short8 tt;
            tt[0] = f2bf(f0.x * 0.125f); tt[1] = f2bf(f0.y * 0.125f);
            tt[2] = f2bf(f0.z * 0.125f); tt[3] = f2bf(f0.w * 0.125f);
            tt[4] = f2bf(f1.x * 0.125f); tt[5] = f2bf(f1.y * 0.125f);
            tt[6] = f2bf(f1.z * 0.125f); tt[7] = f2bf(f1.w * 0.125f);
            qfrag[c] = tt;
        }
    }
    floatx4 o_acc[4];
    #pragma unroll
    for (int dt = 0; dt < 4; ++dt)
        #pragma unroll
        for (int e = 0; e < 4; ++e) o_acc[dt][e] = 0.0f;
    float m_r[4], l_r[4];
    #pragma unroll
    for (int r = 0; r < 4; ++r) { m_r[r] = -1e30f; l_r[r] = 0.0f; }
    for (int t = 0; t <= qi; ++t) {
        __syncthreads();
        {
            const float4* ks = (const float4*)(Kp + (size_t)t * 64 * HD);
            const float4* vs = (const float4*)(Vp + (size_t)t * 64 * HD);
            #pragma unroll
            for (int j = 0; j < 4; ++j) {
                int idx = j * 256 + tid;
                int row = idx >> 4;
                int col = (idx & 15) << 2;
                float4 kf = ks[idx];
                K_lds[row][col + 0] = f2bf(kf.x); K_lds[row][col + 1] = f2bf(kf.y);
                K_lds[row][col + 2] = f2bf(kf.z); K_lds[row][col + 3] = f2bf(kf.w);
                float4 vf = vs[idx];
                Vt_lds[col + 0][row] = f2bf(vf.x); Vt_lds[col + 1][row] = f2bf(vf.y);
                Vt_lds[col + 2][row] = f2bf(vf.z); Vt_lds[col + 3][row] = f2bf(vf.w);
            }
        }
        __syncthreads();
        floatx4 s_acc[4];
        #pragma unroll
        for (int n = 0; n < 4; ++n) {
            const short8 k0 = *(const short8*)&K_lds[n * 16 + l15][dofs];
            const short8 k1 = *(const short8*)&K_lds[n * 16 + l15][dofs + 32];
            floatx4 acc = {0.0f, 0.0f, 0.0f, 0.0f};
            acc = __builtin_amdgcn_mfma_f32_16x16x32_bf16(qfrag[0], k0, acc, 0, 0, 0);
            acc = __builtin_amdgcn_mfma_f32_16x16x32_bf16(qfrag[1], k1, acc, 0, 0, 0);
            s_acc[n] = acc;
        }
        if (t == qi) {
            #pragma unroll
            for (int n = 0; n < 4; ++n)
                #pragma unroll
                for (int r = 0; r < 4; ++r) {
                    int qr = wv * 16 + lg * 4 + r;
                    int kc = n * 16 + l15;
                    if (kc > qr) s_acc[n][r] = -1e30f;
                }
        }
        #pragma unroll
        for (int r = 0; r < 4; ++r) {
            float rmax = fmaxf(fmaxf(s_acc[0][r], s_acc[1][r]),
                               fmaxf(s_acc[2][r], s_acc[3][r]));
            rmax = fmaxf(rmax, __shfl_xor(rmax, 1));
            rmax = fmaxf(rmax, __shfl_xor(rmax, 2));
            rmax = fmaxf(rmax, __shfl_xor(rmax, 4));
            rmax = fmaxf(rmax, __shfl_xor(rmax, 8));
            float mnew  = fmaxf(m_r[r], rmax);
            float alpha = __expf(m_r[r] - mnew);
            m_r[r] = mnew;
            l_r[r] *= alpha;
            #pragma unroll
            for (int dt = 0; dt < 4; ++dt) o_acc[dt][r] *= alpha;
            #pragma unroll
            for (int n = 0; n < 4; ++n) {
                float p = __expf(s_acc[n][r] - mnew);
                l_r[r] += p;
                P_lds[wv][lg * 4 + r][n * 16 + l15] = f2bf(p);
            }
        }
        asm volatile("s_waitcnt lgkmcnt(0)" ::: "memory");
        const short8 p0 = *(const short8*)&P_lds[wv][l15][dofs];
        const short8 p1 = *(const short8*)&P_lds[wv][l15][dofs + 32];
        #pragma unroll
        for (int dt = 0; dt < 4; ++dt) {
            const short8 v0 = *(const short8*)&Vt_lds[dt * 16 + l15][dofs];
            const short8 v1 = *(const short8*)&Vt_lds[dt * 16 + l15][dofs + 32];
            o_acc[dt] = __builtin_amdgcn_mfma_f32_16x16x32_bf16(p0, v0, o_acc[dt], 0, 0, 0);
            o_acc[dt] = __builtin_amdgcn_mfma_f32_16x16x32_bf16(p1, v1, o_acc[dt], 0, 0, 0);
        }
    }
    #pragma unroll
    for (int r = 0; r < 4; ++r) {
        float l = l_r[r];
        l += __shfl_xor(l, 1);
        l += __shfl_xor(l, 2);
        l += __shfl_xor(l, 4);
        l += __shfl_xor(l, 8);
        l_r[r] = 1.0f / l;
    }
    #pragma unroll
    for (int dt = 0; dt < 4; ++dt)
        #pragma unroll
        for (int r = 0; r < 4; ++r) {
            int row = qbase + wv * 16 + lg * 4 + r;
            Op[(size_t)row * HD + dt * 16 + l15] = o_acc[dt][r] * l_r[r];
        }
}

extern "C" void kernel_launch(void* const* d_in, const int* in_sizes, int n_in,
                              void* d_out, int out_size, void* d_ws, size_t ws_size,
                              hipStream_t stream) {
    const float* q = (const float*)d_in[0];
    const float* k = (const float*)d_in[1];
    const float* v = (const float*)d_in[2];
    float* o = (float*)d_out;
    (void)in_sizes; (void)n_in; (void)out_size;

    const size_t elems = (size_t)NBH * SEQ * HD;
    const size_t need  = 2 * elems * sizeof(short);
    if (ws_size >= need) {
        short* kb = (short*)d_ws;
        short* vt = kb + elems;
        prep_kv<<<dim3(NBH * 32), dim3(256), 0, stream>>>(k, v, kb, vt);
        fa_fwd_v16<<<dim3(NBH * NQT), dim3(256), 0, stream>>>(q, kb, vt, o);
    } else {
        fa_fwd_v1<<<dim3(NBH * 32), dim3(256), 0, stream>>>(q, k, v, o);
    }
}

// Round 18
// 49.359 us; speedup vs baseline: 1.6851x; 1.6851x over previous
//
#include <hip/hip_runtime.h>
#include <hip/hip_bf16.h>
#include <cstdint>

#define SEQ   2048
#define HD    64
#define NBH   32
#define QBLK  64
#define KVBLK 64
#define NQT   (SEQ / QBLK)  // 32
// scale = 1/sqrt(64) * log2(e)  (softmax in exp2 domain)
#define QSC   0.18033688011112042f

typedef __attribute__((ext_vector_type(8))) short short8;
typedef __attribute__((ext_vector_type(4))) float floatx4;

#if __has_builtin(__builtin_amdgcn_exp2f)
#define EXP2(x) __builtin_amdgcn_exp2f(x)
#else
#define EXP2(x) __expf((x) * 0.69314718055994531f)
#endif

static __device__ __forceinline__ short f2bf(float f) {
    union { float f; unsigned u; } x; x.f = f;
    return (short)((x.u + 0x7fffu + ((x.u >> 16) & 1u)) >> 16);  // RNE
}
static __device__ __forceinline__ unsigned pkbf(float a, float b) {
    __hip_bfloat162 h = __float22bfloat162_rn(make_float2(a, b));
    union { __hip_bfloat162 h; unsigned u; } c; c.h = h; return c.u;
}

// chunk-rotation swizzle for LINEAR [64][64] tiles (row stride 128B ->
// bank-group == phys chunk): phys = (logical + f(row)) & 7
static __device__ __forceinline__ int swz(int row) {
    return ((row >> 3) + 2 * (row & 7)) & 7;
}

// ---------------- fused prep kernel (proven) ----------------

__global__ __launch_bounds__(256)
void prep_kv(const float* __restrict__ K, const float* __restrict__ V,
             short* __restrict__ Kb, short* __restrict__ Vt) {
    __shared__ __align__(16) short Vs[64][72];
    const int tid = threadIdx.x;
    const int bh = blockIdx.x >> 5;
    const int t  = blockIdx.x & 31;
    const size_t tbase = ((size_t)bh * SEQ + (size_t)t * 64) * HD;

    {
        const float* src = K + tbase;
        short* dst = Kb + tbase;
        #pragma unroll
        for (int i = 0; i < 2; ++i) {
            int off = (i * 256 + tid) * 8;
            float4 a = *(const float4*)(src + off);
            float4 b = *(const float4*)(src + off + 4);
            union { unsigned u[4]; short8 s; } cv;
            cv.u[0] = pkbf(a.x, a.y); cv.u[1] = pkbf(a.z, a.w);
            cv.u[2] = pkbf(b.x, b.y); cv.u[3] = pkbf(b.z, b.w);
            *(short8*)(dst + off) = cv.s;
        }
    }
    {
        const float* src = V + tbase;
        #pragma unroll
        for (int i = 0; i < 4; ++i) {
            int idx = i * 256 + tid;
            int r = idx >> 4; int c = (idx & 15) * 4;
            float4 f = *(const float4*)(src + r * HD + c);
            Vs[c + 0][r] = f2bf(f.x); Vs[c + 1][r] = f2bf(f.y);
            Vs[c + 2][r] = f2bf(f.z); Vs[c + 3][r] = f2bf(f.w);
        }
        __syncthreads();
        short* dst = Vt + (size_t)bh * HD * SEQ + t * 64;
        #pragma unroll
        for (int i = 0; i < 2; ++i) {
            int idx = i * 256 + tid;
            int d = idx >> 3; int j = idx & 7;
            short8 v = *(const short8*)&Vs[d][j * 8];
            *(short8*)(dst + (size_t)d * SEQ + j * 8) = v;
        }
    }
}

// ---------------- main attention kernel (v18) ----------------
// = v15 (best: 40.7us main) with LINEAR [64][64] LDS tiles + chunk-rotation
// swizzle instead of LDK=80 padding. Bank math (128B rows: bank-group = phys
// chunk only): writes phys=(j+wv+2b)&7 uniform; K-frag reads
// phys=(lg+a'+2b'+c)&7 uniform (8 lanes/group, conflict-free); V ~uniform.
// LDS 41 -> 32 KB: v15's 4x41KB > 160KB pool (only 3 blocks resident, the
// stuck 25% occupancy); 32KB fits 5. Staging via PROVEN reg->ds_write path
// (round-17's global_load_lds helper was broken: generic->as(3) ptr trunc).
// launch_bounds(256,5): VGPR cap ~102 >> 52 used, no v16-style spill.

__global__ __launch_bounds__(256, 5)
void fa_fwd_v18(const float* __restrict__ Q, const short* __restrict__ Kg,
                const short* __restrict__ Vtg, float* __restrict__ O)
{
    const int tid  = threadIdx.x;
    const int lane = tid & 63;
    const int wv   = tid >> 6;
    const int l15  = lane & 15;
    const int lg   = lane >> 4;
    const int lg4  = lg * 4;

    const int bh = blockIdx.x & (NBH - 1);
    const int qi = (NQT - 1) - (blockIdx.x >> 5);   // heavy tiles first
    const int qbase = qi * QBLK;

    const float* Qp = Q   + (size_t)bh * SEQ * HD;
    const short* Kp = Kg  + (size_t)bh * SEQ * HD;
    const short* Vp = Vtg + (size_t)bh * HD * SEQ;
    float*       Op = O   + (size_t)bh * SEQ * HD;

    __shared__ __align__(16) short K_lds[2][KVBLK][64];   // 16 KB
    __shared__ __align__(16) short Vt_lds[2][HD][64];     // 16 KB

    // staging: thread handles rows r0 = tid>>3 and r1 = r0+32, logical chunk j0
    const int r0 = tid >> 3, j0 = tid & 7;
    const int r1 = r0 + 32;
    const int kg0 = r0 * HD + j0 * 8, kg1 = r1 * HD + j0 * 8;   // global (shorts)
    const int vg0 = r0 * SEQ + j0 * 8, vg1 = r1 * SEQ + j0 * 8;
    const int kw0 = ((j0 + swz(r0)) & 7) * 8;                   // LDS phys chunk
    const int kw1 = ((j0 + swz(r1)) & 7) * 8;

    // permuted K-row base: call n reads row rowb + {0,4,32,36}[n]
    const int rowb = ((l15 & ~3) << 1) + (l15 & 3);   // 8*(l15>>2) + (l15&3)
    const int kb   = 8 * lg;                           // lane's k base

    // ---- Q fragments (B-operand), scale folded ----
    short8 qf0, qf1;
    {
        const float* src = Qp + (size_t)(qbase + wv * 16 + l15) * HD + lg * 8;
        union { unsigned u[4]; short8 s; } cv;
        float4 f0 = *(const float4*)(src);
        float4 f1 = *(const float4*)(src + 4);
        cv.u[0] = pkbf(f0.x * QSC, f0.y * QSC); cv.u[1] = pkbf(f0.z * QSC, f0.w * QSC);
        cv.u[2] = pkbf(f1.x * QSC, f1.y * QSC); cv.u[3] = pkbf(f1.z * QSC, f1.w * QSC);
        qf0 = cv.s;
        f0 = *(const float4*)(src + 32);
        f1 = *(const float4*)(src + 36);
        cv.u[0] = pkbf(f0.x * QSC, f0.y * QSC); cv.u[1] = pkbf(f0.z * QSC, f0.w * QSC);
        cv.u[2] = pkbf(f1.x * QSC, f1.y * QSC); cv.u[3] = pkbf(f1.z * QSC, f1.w * QSC);
        qf1 = cv.s;
    }

    // all-ones bf16 B-fragment for the l-accumulating MFMA
    short8 ones;
    #pragma unroll
    for (int j = 0; j < 8; ++j) ones[j] = (short)0x3F80;

    // ---- prologue: prefetch tile 0 into registers ----
    short8 krA = *(const short8*)(Kp + kg0);
    short8 krB = *(const short8*)(Kp + kg1);
    short8 vrA = *(const short8*)(Vp + vg0);
    short8 vrB = *(const short8*)(Vp + vg1);

    floatx4 o_acc[4], l_acc;
    #pragma unroll
    for (int dt = 0; dt < 4; ++dt)
        #pragma unroll
        for (int e = 0; e < 4; ++e) o_acc[dt][e] = 0.0f;
    #pragma unroll
    for (int e = 0; e < 4; ++e) l_acc[e] = 0.0f;

    for (int t = 0; t <= qi; ++t) {
        const int buf = t & 1;
        // ---- publish tile t (regs -> LDS), swizzled chunks ----
        *(short8*)&K_lds[buf][r0][kw0]  = krA;
        *(short8*)&K_lds[buf][r1][kw1]  = krB;
        *(short8*)&Vt_lds[buf][r0][kw0] = vrA;
        *(short8*)&Vt_lds[buf][r1][kw1] = vrB;
        __syncthreads();

        // ---- prefetch tile t+1 ----
        if (t < qi) {
            const short* ks = Kp + (size_t)(t + 1) * KVBLK * HD;
            const short* vs = Vp + (t + 1) * KVBLK;
            krA = *(const short8*)(ks + kg0);
            krB = *(const short8*)(ks + kg1);
            vrA = *(const short8*)(vs + vg0);
            vrB = *(const short8*)(vs + vg1);
        }

        // ---- S^T = K (Q*scale)^T with permuted rows (swizzled chunks):
        //      s_acc[n][r] = S[k = kb + roff[n] + r][q = l15] ----
        const int roff[4] = {0, 4, 32, 36};
        floatx4 s_acc[4];
        __builtin_amdgcn_s_setprio(1);
        #pragma unroll
        for (int n = 0; n < 4; ++n) {
            const int row = rowb + roff[n];
            const int pc = (lg + swz(row)) & 7;
            const short* krow = &K_lds[buf][row][0];
            const short8 k0 = *(const short8*)(krow + pc * 8);
            const short8 k1 = *(const short8*)(krow + (pc ^ 4) * 8);
            floatx4 acc = {0.0f, 0.0f, 0.0f, 0.0f};
            acc = __builtin_amdgcn_mfma_f32_16x16x32_bf16(k0, qf0, acc, 0, 0, 0);
            acc = __builtin_amdgcn_mfma_f32_16x16x32_bf16(k1, qf1, acc, 0, 0, 0);
            s_acc[n] = acc;
        }
        __builtin_amdgcn_s_setprio(0);

        // ---- causal mask (diagonal tile only): k_local > q_local ----
        if (t == qi) {
            const int qlocal = wv * 16 + l15;
            #pragma unroll
            for (int n = 0; n < 4; ++n)
                #pragma unroll
                for (int r = 0; r < 4; ++r)
                    if (kb + roff[n] + r > qlocal) s_acc[n][r] = -1e30f;
        }

        // ---- P = exp2(S): shift-free (constant cancels in 1/l) ----
        float p00 = EXP2(s_acc[0][0]), p01 = EXP2(s_acc[0][1]);
        float p02 = EXP2(s_acc[0][2]), p03 = EXP2(s_acc[0][3]);
        float p10 = EXP2(s_acc[1][0]), p11 = EXP2(s_acc[1][1]);
        float p12 = EXP2(s_acc[1][2]), p13 = EXP2(s_acc[1][3]);
        float p20 = EXP2(s_acc[2][0]), p21 = EXP2(s_acc[2][1]);
        float p22 = EXP2(s_acc[2][2]), p23 = EXP2(s_acc[2][3]);
        float p30 = EXP2(s_acc[3][0]), p31 = EXP2(s_acc[3][1]);
        float p32 = EXP2(s_acc[3][2]), p33 = EXP2(s_acc[3][3]);

        // ---- pack P into PV A-fragments (in-register, zero LDS) ----
        short8 p0, p1;
        {
            union { unsigned u[4]; short8 s; } c0, c1;
            c0.u[0] = pkbf(p00, p01); c0.u[1] = pkbf(p02, p03);   // k = kb+0..3
            c0.u[2] = pkbf(p10, p11); c0.u[3] = pkbf(p12, p13);   // k = kb+4..7
            c1.u[0] = pkbf(p20, p21); c1.u[1] = pkbf(p22, p23);   // k = 32+kb+0..3
            c1.u[2] = pkbf(p30, p31); c1.u[3] = pkbf(p32, p33);   // k = 32+kb+4..7
            p0 = c0.s; p1 = c1.s;
        }

        // ---- O += P V ; l += P * ones (matrix pipe does the row-sum) ----
        __builtin_amdgcn_s_setprio(1);
        #pragma unroll
        for (int dt = 0; dt < 4; ++dt) {
            const int row = dt * 16 + l15;
            const int pc = (lg + swz(row)) & 7;
            const short* vrow = &Vt_lds[buf][row][0];
            const short8 v0 = *(const short8*)(vrow + pc * 8);
            const short8 v1 = *(const short8*)(vrow + (pc ^ 4) * 8);
            o_acc[dt] = __builtin_amdgcn_mfma_f32_16x16x32_bf16(p0, v0, o_acc[dt], 0, 0, 0);
            o_acc[dt] = __builtin_amdgcn_mfma_f32_16x16x32_bf16(p1, v1, o_acc[dt], 0, 0, 0);
        }
        l_acc = __builtin_amdgcn_mfma_f32_16x16x32_bf16(p0, ones, l_acc, 0, 0, 0);
        l_acc = __builtin_amdgcn_mfma_f32_16x16x32_bf16(p1, ones, l_acc, 0, 0, 0);
        __builtin_amdgcn_s_setprio(0);
    }

    // ---- finalize: l_acc[e] = l[q = lg4+e] in every lane; no shuffles ----
    #pragma unroll
    for (int e = 0; e < 4; ++e) {
        const float li = 1.0f / l_acc[e];
        const int row = qbase + wv * 16 + lg4 + e;
        #pragma unroll
        for (int dt = 0; dt < 4; ++dt)
            Op[(size_t)row * HD + dt * 16 + l15] = o_acc[dt][e] * li;
    }
}

// ---------------- fallback (round-1 kernel, proven) if ws too small ----------------

__global__ __launch_bounds__(256, 2)
void fa_fwd_v1(const float* __restrict__ Q, const float* __restrict__ K,
               const float* __restrict__ V, float* __restrict__ O)
{
    const int tid  = threadIdx.x;
    const int lane = tid & 63;
    const int wv   = tid >> 6;
    const int l15  = lane & 15;
    const int lg   = lane >> 4;
    const int dofs = lg * 8;
    const int bh = blockIdx.x & (NBH - 1);
    const int qi = 31 - (blockIdx.x >> 5);
    const size_t base = (size_t)bh * SEQ * HD;
    const float* Qp = Q + base; const float* Kp = K + base;
    const float* Vp = V + base; float* Op = O + base;
    const int qbase = qi * 64;
    __shared__ __align__(16) short K_lds[64][72];
    __shared__ __align__(16) short Vt_lds[HD][72];
    __shared__ __align__(16) short P_lds[4][16][72];
    short8 qfrag[2];
    {
        const float* src = Qp + (size_t)(qbase + wv * 16 + l15) * HD + dofs;
        #pragma unroll
        for (int c = 0; c < 2; ++c) {
            float4 f0 = *(const float4*)(src + 32 * c);
            float4 f1 = *(const float4*)(src + 32 * c + 4);
            short8 tt;
            tt[0] = f2bf(f0.x * 0.125f); tt[1] = f2bf(f0.y * 0.125f);
            tt[2] = f2bf(f0.z * 0.125f); tt[3] = f2bf(f0.w * 0.125f);
            tt[4] = f2bf(f1.x * 0.125f); tt[5] = f2bf(f1.y * 0.125f);
            tt[6] = f2bf(f1.z * 0.125f); tt[7] = f2bf(f1.w * 0.125f);
            qfrag[c] = tt;
        }
    }
    floatx4 o_acc[4];
    #pragma unroll
    for (int dt = 0; dt < 4; ++dt)
        #pragma unroll
        for (int e = 0; e < 4; ++e) o_acc[dt][e] = 0.0f;
    float m_r[4], l_r[4];
    #pragma unroll
    for (int r = 0; r < 4; ++r) { m_r[r] = -1e30f; l_r[r] = 0.0f; }
    for (int t = 0; t <= qi; ++t) {
        __syncthreads();
        {
            const float4* ks = (const float4*)(Kp + (size_t)t * 64 * HD);
            const float4* vs = (const float4*)(Vp + (size_t)t * 64 * HD);
            #pragma unroll
            for (int j = 0; j < 4; ++j) {
                int idx = j * 256 + tid;
                int row = idx >> 4;
                int col = (idx & 15) << 2;
                float4 kf = ks[idx];
                K_lds[row][col + 0] = f2bf(kf.x); K_lds[row][col + 1] = f2bf(kf.y);
                K_lds[row][col + 2] = f2bf(kf.z); K_lds[row][col + 3] = f2bf(kf.w);
                float4 vf = vs[idx];
                Vt_lds[col + 0][row] = f2bf(vf.x); Vt_lds[col + 1][row] = f2bf(vf.y);
                Vt_lds[col + 2][row] = f2bf(vf.z); Vt_lds[col + 3][row] = f2bf(vf.w);
            }
        }
        __syncthreads();
        floatx4 s_acc[4];
        #pragma unroll
        for (int n = 0; n < 4; ++n) {
            const short8 k0 = *(const short8*)&K_lds[n * 16 + l15][dofs];
            const short8 k1 = *(const short8*)&K_lds[n * 16 + l15][dofs + 32];
            floatx4 acc = {0.0f, 0.0f, 0.0f, 0.0f};
            acc = __builtin_amdgcn_mfma_f32_16x16x32_bf16(qfrag[0], k0, acc, 0, 0, 0);
            acc = __builtin_amdgcn_mfma_f32_16x16x32_bf16(qfrag[1], k1, acc, 0, 0, 0);
            s_acc[n] = acc;
        }
        if (t == qi) {
            #pragma unroll
            for (int n = 0; n < 4; ++n)
                #pragma unroll
                for (int r = 0; r < 4; ++r) {
                    int qr = wv * 16 + lg * 4 + r;
                    int kc = n * 16 + l15;
                    if (kc > qr) s_acc[n][r] = -1e30f;
                }
        }
        #pragma unroll
        for (int r = 0; r < 4; ++r) {
            float rmax = fmaxf(fmaxf(s_acc[0][r], s_acc[1][r]),
                               fmaxf(s_acc[2][r], s_acc[3][r]));
            rmax = fmaxf(rmax, __shfl_xor(rmax, 1));
            rmax = fmaxf(rmax, __shfl_xor(rmax, 2));
            rmax = fmaxf(rmax, __shfl_xor(rmax, 4));
            rmax = fmaxf(rmax, __shfl_xor(rmax, 8));
            float mnew  = fmaxf(m_r[r], rmax);
            float alpha = __expf(m_r[r] - mnew);
            m_r[r] = mnew;
            l_r[r] *= alpha;
            #pragma unroll
            for (int dt = 0; dt < 4; ++dt) o_acc[dt][r] *= alpha;
            #pragma unroll
            for (int n = 0; n < 4; ++n) {
                float p = __expf(s_acc[n][r] - mnew);
                l_r[r] += p;
                P_lds[wv][lg * 4 + r][n * 16 + l15] = f2bf(p);
            }
        }
        asm volatile("s_waitcnt lgkmcnt(0)" ::: "memory");
        const short8 p0 = *(const short8*)&P_lds[wv][l15][dofs];
        const short8 p1 = *(const short8*)&P_lds[wv][l15][dofs + 32];
        #pragma unroll
        for (int dt = 0; dt < 4; ++dt) {
            const short8 v0 = *(const short8*)&Vt_lds[dt * 16 + l15][dofs];
            const short8 v1 = *(const short8*)&Vt_lds[dt * 16 + l15][dofs + 32];
            o_acc[dt] = __builtin_amdgcn_mfma_f32_16x16x32_bf16(p0, v0, o_acc[dt], 0, 0, 0);
            o_acc[dt] = __builtin_amdgcn_mfma_f32_16x16x32_bf16(p1, v1, o_acc[dt], 0, 0, 0);
        }
    }
    #pragma unroll
    for (int r = 0; r < 4; ++r) {
        float l = l_r[r];
        l += __shfl_xor(l, 1);
        l += __shfl_xor(l, 2);
        l += __shfl_xor(l, 4);
        l += __shfl_xor(l, 8);
        l_r[r] = 1.0f / l;
    }
    #pragma unroll
    for (int dt = 0; dt < 4; ++dt)
        #pragma unroll
        for (int r = 0; r < 4; ++r) {
            int row = qbase + wv * 16 + lg * 4 + r;
            Op[(size_t)row * HD + dt * 16 + l15] = o_acc[dt][r] * l_r[r];
        }
}

extern "C" void kernel_launch(void* const* d_in, const int* in_sizes, int n_in,
                              void* d_out, int out_size, void* d_ws, size_t ws_size,
                              hipStream_t stream) {
    const float* q = (const float*)d_in[0];
    const float* k = (const float*)d_in[1];
    const float* v = (const float*)d_in[2];
    float* o = (float*)d_out;
    (void)in_sizes; (void)n_in; (void)out_size;

    const size_t elems = (size_t)NBH * SEQ * HD;
    const size_t need  = 2 * elems * sizeof(short);
    if (ws_size >= need) {
        short* kb = (short*)d_ws;
        short* vt = kb + elems;
        prep_kv<<<dim3(NBH * 32), dim3(256), 0, stream>>>(k, v, kb, vt);
        fa_fwd_v18<<<dim3(NBH * NQT), dim3(256), 0, stream>>>(q, kb, vt, o);
    } else {
        fa_fwd_v1<<<dim3(NBH * 32), dim3(256), 0, stream>>>(q, k, v, o);
    }
}

// Round 19
// 44.339 us; speedup vs baseline: 1.8759x; 1.1132x over previous
//
#include <hip/hip_runtime.h>
#include <hip/hip_bf16.h>
#include <cstdint>

#define SEQ   2048
#define HD    64
#define NBH   32
#define QBLK  64
#define KVBLK 64
#define NQT   (SEQ / QBLK)  // 32
#define LDK   80            // 160B rows: bank-group = (2*row + chunk) mod 8 ->
                            // uniform for our K-read rows {8a+b}, V-reads, writes
// scale = 1/sqrt(64) * log2(e)  (softmax in exp2 domain)
#define QSC   0.18033688011112042f

typedef __attribute__((ext_vector_type(8))) short short8;
typedef __attribute__((ext_vector_type(4))) float floatx4;

#if __has_builtin(__builtin_amdgcn_exp2f)
#define EXP2(x) __builtin_amdgcn_exp2f(x)
#else
#define EXP2(x) __expf((x) * 0.69314718055994531f)
#endif

static __device__ __forceinline__ short f2bf(float f) {
    union { float f; unsigned u; } x; x.f = f;
    return (short)((x.u + 0x7fffu + ((x.u >> 16) & 1u)) >> 16);  // RNE
}
static __device__ __forceinline__ unsigned pkbf(float a, float b) {
    __hip_bfloat162 h = __float22bfloat162_rn(make_float2(a, b));
    union { __hip_bfloat162 h; unsigned u; } c; c.h = h; return c.u;
}

// ---------------- fused prep kernel (proven) ----------------

__global__ __launch_bounds__(256)
void prep_kv(const float* __restrict__ K, const float* __restrict__ V,
             short* __restrict__ Kb, short* __restrict__ Vt) {
    __shared__ __align__(16) short Vs[64][72];
    const int tid = threadIdx.x;
    const int bh = blockIdx.x >> 5;
    const int t  = blockIdx.x & 31;
    const size_t tbase = ((size_t)bh * SEQ + (size_t)t * 64) * HD;

    {
        const float* src = K + tbase;
        short* dst = Kb + tbase;
        #pragma unroll
        for (int i = 0; i < 2; ++i) {
            int off = (i * 256 + tid) * 8;
            float4 a = *(const float4*)(src + off);
            float4 b = *(const float4*)(src + off + 4);
            union { unsigned u[4]; short8 s; } cv;
            cv.u[0] = pkbf(a.x, a.y); cv.u[1] = pkbf(a.z, a.w);
            cv.u[2] = pkbf(b.x, b.y); cv.u[3] = pkbf(b.z, b.w);
            *(short8*)(dst + off) = cv.s;
        }
    }
    {
        const float* src = V + tbase;
        #pragma unroll
        for (int i = 0; i < 4; ++i) {
            int idx = i * 256 + tid;
            int r = idx >> 4; int c = (idx & 15) * 4;
            float4 f = *(const float4*)(src + r * HD + c);
            Vs[c + 0][r] = f2bf(f.x); Vs[c + 1][r] = f2bf(f.y);
            Vs[c + 2][r] = f2bf(f.z); Vs[c + 3][r] = f2bf(f.w);
        }
        __syncthreads();
        short* dst = Vt + (size_t)bh * HD * SEQ + t * 64;
        #pragma unroll
        for (int i = 0; i < 2; ++i) {
            int idx = i * 256 + tid;
            int d = idx >> 3; int j = idx & 7;
            short8 v = *(const short8*)&Vs[d][j * 8];
            *(short8*)(dst + (size_t)d * SEQ + j * 8) = v;
        }
    }
}

// ---------------- main attention kernel (v15 — session best) ----------------
// Structure: static-shift-free softmax P=exp2(S) (constant cancels in 1/l),
// zero-LDS P via K-row permutation {0,4,32,36} (QK^T output lands directly in
// the PV A-fragment layout), l accumulated via all-ones-MFMA (no lsum tree,
// no finalize shuffles), LDK=80 padding (the only empirically-effective
// bank-conflict fix: 4.3e6 -> 2.16e6), double-buffered K/V with one barrier
// per tile and register prefetch, 1024 heavy-first blocks (bh-major => all
// blocks of one bh land on one XCD; 4 bh x 512KB = 2MB L2-resident).

__global__ __launch_bounds__(256, 4)
void fa_fwd_v15(const float* __restrict__ Q, const short* __restrict__ Kg,
                const short* __restrict__ Vtg, float* __restrict__ O)
{
    const int tid  = threadIdx.x;
    const int lane = tid & 63;
    const int wv   = tid >> 6;
    const int l15  = lane & 15;
    const int lg   = lane >> 4;
    const int lg4  = lg * 4;
    const int dofs = lg * 8;

    const int bh = blockIdx.x & (NBH - 1);
    const int qi = (NQT - 1) - (blockIdx.x >> 5);   // heavy tiles first
    const int qbase = qi * QBLK;

    const float* Qp = Q   + (size_t)bh * SEQ * HD;
    const short* Kp = Kg  + (size_t)bh * SEQ * HD;
    const short* Vp = Vtg + (size_t)bh * HD * SEQ;
    float*       Op = O   + (size_t)bh * SEQ * HD;

    __shared__ __align__(16) short K_lds[2][KVBLK][LDK];
    __shared__ __align__(16) short Vt_lds[2][HD][LDK];

    const int r0 = tid >> 3, j0 = tid & 7;
    const int r1 = r0 + 32;                      // (tid+256)>>3
    const int kg0 = r0 * HD + j0 * 8, kg1 = r1 * HD + j0 * 8;
    const int vg0 = r0 * SEQ + j0 * 8, vg1 = r1 * SEQ + j0 * 8;

    // permuted K-row base: call n reads row rowb + {0,4,32,36}[n]
    const int rowb = ((l15 & ~3) << 1) + (l15 & 3);   // 8*(l15>>2) + (l15&3)
    const int kb   = 8 * lg;                           // lane's k base

    // ---- Q fragments (B-operand), scale folded ----
    short8 qf0, qf1;
    {
        const float* src = Qp + (size_t)(qbase + wv * 16 + l15) * HD + dofs;
        union { unsigned u[4]; short8 s; } cv;
        float4 f0 = *(const float4*)(src);
        float4 f1 = *(const float4*)(src + 4);
        cv.u[0] = pkbf(f0.x * QSC, f0.y * QSC); cv.u[1] = pkbf(f0.z * QSC, f0.w * QSC);
        cv.u[2] = pkbf(f1.x * QSC, f1.y * QSC); cv.u[3] = pkbf(f1.z * QSC, f1.w * QSC);
        qf0 = cv.s;
        f0 = *(const float4*)(src + 32);
        f1 = *(const float4*)(src + 36);
        cv.u[0] = pkbf(f0.x * QSC, f0.y * QSC); cv.u[1] = pkbf(f0.z * QSC, f0.w * QSC);
        cv.u[2] = pkbf(f1.x * QSC, f1.y * QSC); cv.u[3] = pkbf(f1.z * QSC, f1.w * QSC);
        qf1 = cv.s;
    }

    // all-ones bf16 B-fragment for the l-accumulating MFMA
    short8 ones;
    #pragma unroll
    for (int j = 0; j < 8; ++j) ones[j] = (short)0x3F80;

    // ---- prologue: prefetch tile 0 into registers ----
    short8 krA = *(const short8*)(Kp + kg0);
    short8 krB = *(const short8*)(Kp + kg1);
    short8 vrA = *(const short8*)(Vp + vg0);
    short8 vrB = *(const short8*)(Vp + vg1);

    floatx4 o_acc[4], l_acc;
    #pragma unroll
    for (int dt = 0; dt < 4; ++dt)
        #pragma unroll
        for (int e = 0; e < 4; ++e) o_acc[dt][e] = 0.0f;
    #pragma unroll
    for (int e = 0; e < 4; ++e) l_acc[e] = 0.0f;

    for (int t = 0; t <= qi; ++t) {
        const int buf = t & 1;
        // ---- publish tile t (regs -> LDS), plain layout ----
        *(short8*)&K_lds[buf][r0][j0 * 8]  = krA;
        *(short8*)&K_lds[buf][r1][j0 * 8]  = krB;
        *(short8*)&Vt_lds[buf][r0][j0 * 8] = vrA;
        *(short8*)&Vt_lds[buf][r1][j0 * 8] = vrB;
        __syncthreads();

        // ---- prefetch tile t+1 ----
        if (t < qi) {
            const short* ks = Kp + (size_t)(t + 1) * KVBLK * HD;
            const short* vs = Vp + (t + 1) * KVBLK;
            krA = *(const short8*)(ks + kg0);
            krB = *(const short8*)(ks + kg1);
            vrA = *(const short8*)(vs + vg0);
            vrB = *(const short8*)(vs + vg1);
        }

        // ---- S^T = K (Q*scale)^T with permuted rows:
        //      s_acc[n][r] = S[k = kb + roff[n] + r][q = l15] ----
        const int roff[4] = {0, 4, 32, 36};
        floatx4 s_acc[4];
        __builtin_amdgcn_s_setprio(1);
        #pragma unroll
        for (int n = 0; n < 4; ++n) {
            const short* krow = &K_lds[buf][rowb + roff[n]][0];
            const short8 k0 = *(const short8*)(krow + dofs);
            const short8 k1 = *(const short8*)(krow + dofs + 32);
            floatx4 acc = {0.0f, 0.0f, 0.0f, 0.0f};
            acc = __builtin_amdgcn_mfma_f32_16x16x32_bf16(k0, qf0, acc, 0, 0, 0);
            acc = __builtin_amdgcn_mfma_f32_16x16x32_bf16(k1, qf1, acc, 0, 0, 0);
            s_acc[n] = acc;
        }
        __builtin_amdgcn_s_setprio(0);

        // ---- causal mask (diagonal tile only): k_local > q_local ----
        if (t == qi) {
            const int qlocal = wv * 16 + l15;
            #pragma unroll
            for (int n = 0; n < 4; ++n)
                #pragma unroll
                for (int r = 0; r < 4; ++r)
                    if (kb + roff[n] + r > qlocal) s_acc[n][r] = -1e30f;
        }

        // ---- P = exp2(S): no shift (cancels in 1/l), no max machinery ----
        float p00 = EXP2(s_acc[0][0]), p01 = EXP2(s_acc[0][1]);
        float p02 = EXP2(s_acc[0][2]), p03 = EXP2(s_acc[0][3]);
        float p10 = EXP2(s_acc[1][0]), p11 = EXP2(s_acc[1][1]);
        float p12 = EXP2(s_acc[1][2]), p13 = EXP2(s_acc[1][3]);
        float p20 = EXP2(s_acc[2][0]), p21 = EXP2(s_acc[2][1]);
        float p22 = EXP2(s_acc[2][2]), p23 = EXP2(s_acc[2][3]);
        float p30 = EXP2(s_acc[3][0]), p31 = EXP2(s_acc[3][1]);
        float p32 = EXP2(s_acc[3][2]), p33 = EXP2(s_acc[3][3]);

        // ---- pack P into PV A-fragments (in-register, zero LDS) ----
        short8 p0, p1;
        {
            union { unsigned u[4]; short8 s; } c0, c1;
            c0.u[0] = pkbf(p00, p01); c0.u[1] = pkbf(p02, p03);   // k = kb+0..3
            c0.u[2] = pkbf(p10, p11); c0.u[3] = pkbf(p12, p13);   // k = kb+4..7
            c1.u[0] = pkbf(p20, p21); c1.u[1] = pkbf(p22, p23);   // k = 32+kb+0..3
            c1.u[2] = pkbf(p30, p31); c1.u[3] = pkbf(p32, p33);   // k = 32+kb+4..7
            p0 = c0.s; p1 = c1.s;
        }

        // ---- O += P V ; l += P * ones (matrix pipe does the row-sum) ----
        __builtin_amdgcn_s_setprio(1);
        #pragma unroll
        for (int dt = 0; dt < 4; ++dt) {
            const short8 v0 = *(const short8*)&Vt_lds[buf][dt * 16 + l15][dofs];
            const short8 v1 = *(const short8*)&Vt_lds[buf][dt * 16 + l15][dofs + 32];
            o_acc[dt] = __builtin_amdgcn_mfma_f32_16x16x32_bf16(p0, v0, o_acc[dt], 0, 0, 0);
            o_acc[dt] = __builtin_amdgcn_mfma_f32_16x16x32_bf16(p1, v1, o_acc[dt], 0, 0, 0);
        }
        l_acc = __builtin_amdgcn_mfma_f32_16x16x32_bf16(p0, ones, l_acc, 0, 0, 0);
        l_acc = __builtin_amdgcn_mfma_f32_16x16x32_bf16(p1, ones, l_acc, 0, 0, 0);
        __builtin_amdgcn_s_setprio(0);
    }

    // ---- finalize: l_acc[e] = l[q = lg4+e] in every lane; no shuffles ----
    #pragma unroll
    for (int e = 0; e < 4; ++e) {
        const float li = 1.0f / l_acc[e];
        const int row = qbase + wv * 16 + lg4 + e;
        #pragma unroll
        for (int dt = 0; dt < 4; ++dt)
            Op[(size_t)row * HD + dt * 16 + l15] = o_acc[dt][e] * li;
    }
}

// ---------------- fallback (round-1 kernel, proven) if ws too small ----------------

__global__ __launch_bounds__(256, 2)
void fa_fwd_v1(const float* __restrict__ Q, const float* __restrict__ K,
               const float* __restrict__ V, float* __restrict__ O)
{
    const int tid  = threadIdx.x;
    const int lane = tid & 63;
    const int wv   = tid >> 6;
    const int l15  = lane & 15;
    const int lg   = lane >> 4;
    const int dofs = lg * 8;
    const int bh = blockIdx.x & (NBH - 1);
    const int qi = 31 - (blockIdx.x >> 5);
    const size_t base = (size_t)bh * SEQ * HD;
    const float* Qp = Q + base; const float* Kp = K + base;
    const float* Vp = V + base; float* Op = O + base;
    const int qbase = qi * 64;
    __shared__ __align__(16) short K_lds[64][72];
    __shared__ __align__(16) short Vt_lds[HD][72];
    __shared__ __align__(16) short P_lds[4][16][72];
    short8 qfrag[2];
    {
        const float* src = Qp + (size_t)(qbase + wv * 16 + l15) * HD + dofs;
        #pragma unroll
        for (int c = 0; c < 2; ++c) {
            float4 f0 = *(const float4*)(src + 32 * c);
            float4 f1 = *(const float4*)(src + 32 * c + 4);
            short8 tt;
            tt[0] = f2bf(f0.x * 0.125f); tt[1] = f2bf(f0.y * 0.125f);
            tt[2] = f2bf(f0.z * 0.125f); tt[3] = f2bf(f0.w * 0.125f);
            tt[4] = f2bf(f1.x * 0.125f); tt[5] = f2bf(f1.y * 0.125f);
            tt[6] = f2bf(f1.z * 0.125f); tt[7] = f2bf(f1.w * 0.125f);
            qfrag[c] = tt;
        }
    }
    floatx4 o_acc[4];
    #pragma unroll
    for (int dt = 0; dt < 4; ++dt)
        #pragma unroll
        for (int e = 0; e < 4; ++e) o_acc[dt][e] = 0.0f;
    float m_r[4], l_r[4];
    #pragma unroll
    for (int r = 0; r < 4; ++r) { m_r[r] = -1e30f; l_r[r] = 0.0f; }
    for (int t = 0; t <= qi; ++t) {
        __syncthreads();
        {
            const float4* ks = (const float4*)(Kp + (size_t)t * 64 * HD);
            const float4* vs = (const float4*)(Vp + (size_t)t * 64 * HD);
            #pragma unroll
            for (int j = 0; j < 4; ++j) {
                int idx = j * 256 + tid;
                int row = idx >> 4;
                int col = (idx & 15) << 2;
                float4 kf = ks[idx];
                K_lds[row][col + 0] = f2bf(kf.x); K_lds[row][col + 1] = f2bf(kf.y);
                K_lds[row][col + 2] = f2bf(kf.z); K_lds[row][col + 3] = f2bf(kf.w);
                float4 vf = vs[idx];
                Vt_lds[col + 0][row] = f2bf(vf.x); Vt_lds[col + 1][row] = f2bf(vf.y);
                Vt_lds[col + 2][row] = f2bf(vf.z); Vt_lds[col + 3][row] = f2bf(vf.w);
            }
        }
        __syncthreads();
        floatx4 s_acc[4];
        #pragma unroll
        for (int n = 0; n < 4; ++n) {
            const short8 k0 = *(const short8*)&K_lds[n * 16 + l15][dofs];
            const short8 k1 = *(const short8*)&K_lds[n * 16 + l15][dofs + 32];
            floatx4 acc = {0.0f, 0.0f, 0.0f, 0.0f};
            acc = __builtin_amdgcn_mfma_f32_16x16x32_bf16(qfrag[0], k0, acc, 0, 0, 0);
            acc = __builtin_amdgcn_mfma_f32_16x16x32_bf16(qfrag[1], k1, acc, 0, 0, 0);
            s_acc[n] = acc;
        }
        if (t == qi) {
            #pragma unroll
            for (int n = 0; n < 4; ++n)
                #pragma unroll
                for (int r = 0; r < 4; ++r) {
                    int qr = wv * 16 + lg * 4 + r;
                    int kc = n * 16 + l15;
                    if (kc > qr) s_acc[n][r] = -1e30f;
                }
        }
        #pragma unroll
        for (int r = 0; r < 4; ++r) {
            float rmax = fmaxf(fmaxf(s_acc[0][r], s_acc[1][r]),
                               fmaxf(s_acc[2][r], s_acc[3][r]));
            rmax = fmaxf(rmax, __shfl_xor(rmax, 1));
            rmax = fmaxf(rmax, __shfl_xor(rmax, 2));
            rmax = fmaxf(rmax, __shfl_xor(rmax, 4));
            rmax = fmaxf(rmax, __shfl_xor(rmax, 8));
            float mnew  = fmaxf(m_r[r], rmax);
            float alpha = __expf(m_r[r] - mnew);
            m_r[r] = mnew;
            l_r[r] *= alpha;
            #pragma unroll
            for (int dt = 0; dt < 4; ++dt) o_acc[dt][r] *= alpha;
            #pragma unroll
            for (int n = 0; n < 4; ++n) {
                float p = __expf(s_acc[n][r] - mnew);
                l_r[r] += p;
                P_lds[wv][lg * 4 + r][n * 16 + l15] = f2bf(p);
            }
        }
        asm volatile("s_waitcnt lgkmcnt(0)" ::: "memory");
        const short8 p0 = *(const short8*)&P_lds[wv][l15][dofs];
        const short8 p1 = *(const short8*)&P_lds[wv][l15][dofs + 32];
        #pragma unroll
        for (int dt = 0; dt < 4; ++dt) {
            const short8 v0 = *(const short8*)&Vt_lds[dt * 16 + l15][dofs];
            const short8 v1 = *(const short8*)&Vt_lds[dt * 16 + l15][dofs + 32];
            o_acc[dt] = __builtin_amdgcn_mfma_f32_16x16x32_bf16(p0, v0, o_acc[dt], 0, 0, 0);
            o_acc[dt] = __builtin_amdgcn_mfma_f32_16x16x32_bf16(p1, v1, o_acc[dt], 0, 0, 0);
        }
    }
    #pragma unroll
    for (int r = 0; r < 4; ++r) {
        float l = l_r[r];
        l += __shfl_xor(l, 1);
        l += __shfl_xor(l, 2);
        l += __shfl_xor(l, 4);
        l += __shfl_xor(l, 8);
        l_r[r] = 1.0f / l;
    }
    #pragma unroll
    for (int dt = 0; dt < 4; ++dt)
        #pragma unroll
        for (int r = 0; r < 4; ++r) {
            int row = qbase + wv * 16 + lg * 4 + r;
            Op[(size_t)row * HD + dt * 16 + l15] = o_acc[dt][r] * l_r[r];
        }
}

extern "C" void kernel_launch(void* const* d_in, const int* in_sizes, int n_in,
                              void* d_out, int out_size, void* d_ws, size_t ws_size,
                              hipStream_t stream) {
    const float* q = (const float*)d_in[0];
    const float* k = (const float*)d_in[1];
    const float* v = (const float*)d_in[2];
    float* o = (float*)d_out;
    (void)in_sizes; (void)n_in; (void)out_size;

    const size_t elems = (size_t)NBH * SEQ * HD;
    const size_t need  = 2 * elems * sizeof(short);
    if (ws_size >= need) {
        short* kb = (short*)d_ws;
        short* vt = kb + elems;
        prep_kv<<<dim3(NBH * 32), dim3(256), 0, stream>>>(k, v, kb, vt);
        fa_fwd_v15<<<dim3(NBH * NQT), dim3(256), 0, stream>>>(q, kb, vt, o);
    } else {
        fa_fwd_v1<<<dim3(NBH * 32), dim3(256), 0, stream>>>(q, k, v, o);
    }
}